// Round 7
// baseline (290.559 us; speedup 1.0000x reference)
//
#include <hip/hip_runtime.h>
#include <hip/hip_bf16.h>

// B=4, S=2048, D=1024, H=16, DK=DV=64. Inputs f32, output f32 (confirmed r8).
// MFMA math bf16 with f32 accum. Round 16:
//  - flash: sequential-pair blocks (64-row q-tiles p and 31-p): every block
//    exactly 33 iterations -> zero tail idle; 4-wave/256-thr blocks, 1024
//    blocks = exactly 4/CU; no wave-skip (all waves active every j-tile).
//  - qkv: emb f32->bf16 conversion fused into A-staging (cvtpk), embconv
//    kernel DELETED (-192 MB streaming round-trip). B stays global_load_lds.
//  - oproj/wtrans unchanged.

typedef __attribute__((ext_vector_type(8))) short bf16x8;
typedef __attribute__((ext_vector_type(4))) float f32x4;
typedef __attribute__((ext_vector_type(4))) unsigned int u32x4;
typedef __attribute__((ext_vector_type(2))) unsigned int u32x2;

#define MFMA16(a, b, c) __builtin_amdgcn_mfma_f32_16x16x32_bf16((a), (b), (c), 0, 0, 0)

#define LOG2E 1.44269504088896340736f
#define BIG_NEG (-3.0e38f)
#define DEFER_THR 10.0f  // log2-domain; P bounded by 2^10 when rescale skipped

__device__ __forceinline__ unsigned short f2bf(float f) {
  union { float f; unsigned int i; } x; x.f = f;
  unsigned int lsb = (x.i >> 16) & 1;
  x.i += 0x7fffu + lsb;  // RNE (finite inputs only)
  return (unsigned short)(x.i >> 16);
}

__device__ __forceinline__ unsigned int cvtpk(float lo, float hi) {
  unsigned int r;
  asm("v_cvt_pk_bf16_f32 %0, %1, %2" : "=v"(r) : "v"(lo), "v"(hi));
  return r;
}

// global -> LDS direct DMA, 16B per lane. lds dest must be wave-uniform base;
// HW writes base + lane*16. Global src is per-lane.
__device__ __forceinline__ void gl16(const unsigned short* g, void* l) {
  __builtin_amdgcn_global_load_lds(
      (const __attribute__((address_space(1))) unsigned int*)g,
      (__attribute__((address_space(3))) unsigned int*)l, 16, 0, 0);
}

// ---------------------------------------------------------------------------
// Batched transpose + downconvert: in f32 [batch][R][C] -> out bf16 [batch][C][R]
// ---------------------------------------------------------------------------
__global__ void wtrans_kernel(const float* __restrict__ in,
                              unsigned short* __restrict__ out, int R, int C) {
  __shared__ unsigned short tile[32][33];
  const int bz = blockIdx.z;
  const int c0 = blockIdx.x * 32, r0 = blockIdx.y * 32;
  const float* ip = in + (size_t)bz * R * C;
  unsigned short* op = out + (size_t)bz * R * C;
  const int tx = threadIdx.x, ty = threadIdx.y;  // (32, 8)
#pragma unroll
  for (int i = 0; i < 32; i += 8)
    tile[ty + i][tx] = f2bf(ip[(size_t)(r0 + ty + i) * C + (c0 + tx)]);
  __syncthreads();
#pragma unroll
  for (int i = 0; i < 32; i += 8)
    op[(size_t)(c0 + ty + i) * R + (r0 + tx)] = tile[tx][ty + i];
}

// ---------------------------------------------------------------------------
// QKV projection, GROUP of nb batches: embF f32 [nb*2048][1024] x WtT bf16
// [h][c][d] -> Q (pre-scaled by 0.125*log2e), K bf16 [(b*16+h)][s][64],
// V transposed -> Vt [(b*16+h)][dv][s].
// 1D grid nwg = 24*MB_CNT, XCD-chunked swizzle, m-major block order.
// A staged via reg-load f32 + cvtpk -> padded As[128][40] (fused convert);
// B staged via global_load_lds width=16 into linear Bs[128][32].
// ---------------------------------------------------------------------------
__global__ __launch_bounds__(256, 4)
void qkv_kernel(const float* __restrict__ embF,
                const unsigned short* __restrict__ WqT,
                const unsigned short* __restrict__ WkT,
                const unsigned short* __restrict__ WvT,
                unsigned short* __restrict__ QG,
                unsigned short* __restrict__ KG,
                unsigned short* __restrict__ VtG) {
  const int nwg = gridDim.x;                       // 24 * MB_CNT, %8 == 0
  const int wg = blockIdx.x;
  const int swz = (wg & 7) * (nwg >> 3) + (wg >> 3);
  const int mb = swz / 24;                         // emb panel index
  const int rem = swz - mb * 24;
  const int t = rem >> 3;                          // 0=Q, 1=K, 2=V
  const int m0 = mb * 128;
  const int n0 = (rem & 7) * 128;
  const int b = m0 >> 11;                          // local batch
  const int sloc = m0 & 2047;
  const unsigned short* Wt =
      (t == 0 ? WqT : (t == 1 ? WkT : WvT)) + (size_t)(n0 >> 6) * 64 * 1024;

  __shared__ __align__(16) unsigned short As[128][40];   // [m][k], +8 pad
  __shared__ __align__(16) unsigned short Bs[128 * 32];  // [n][k] linear

  const int tid = threadIdx.x;
  const int lane = tid & 63, w = tid >> 6;
  const int q4 = lane >> 4, l16 = lane & 15;
  const int lr = lane >> 2, lc = (lane & 3) * 8;   // B staging row/col-in-BK
  const int arow = tid >> 1, acol = (tid & 1) * 16;  // A staging

  f32x4 acc[4][4] = {};

  const float* aptr = &embF[(size_t)(m0 + arow) * 1024 + acol];
  const unsigned short* gb0 = &Wt[(size_t)(w * 32 + lr) * 1024 + lc];
  const unsigned short* gb1 = gb0 + 16 * 1024;
  char* lb0 = (char*)Bs + w * 2048;

  for (int k0 = 0; k0 < 1024; k0 += 32) {
    __syncthreads();                 // prev tile's ds_reads complete
    gl16(gb0 + k0, lb0);             // async B staging (overlaps A convert)
    gl16(gb1 + k0, lb0 + 1024);
    {
      const float4 v0 = *(const float4*)&aptr[k0];
      const float4 v1 = *(const float4*)&aptr[k0 + 4];
      const float4 v2 = *(const float4*)&aptr[k0 + 8];
      const float4 v3 = *(const float4*)&aptr[k0 + 12];
      u32x4 p0, p1;
      p0[0] = cvtpk(v0.x, v0.y); p0[1] = cvtpk(v0.z, v0.w);
      p0[2] = cvtpk(v1.x, v1.y); p0[3] = cvtpk(v1.z, v1.w);
      p1[0] = cvtpk(v2.x, v2.y); p1[1] = cvtpk(v2.z, v2.w);
      p1[2] = cvtpk(v3.x, v3.y); p1[3] = cvtpk(v3.z, v3.w);
      *(u32x4*)&As[arow][acol]     = p0;
      *(u32x4*)&As[arow][acol + 8] = p1;
    }
    __syncthreads();                 // drains vmcnt + lgkm: tiles visible

    bf16x8 af[4], bfr[4];
    if (t == 2) {
      // V^T = mfma(B, A): A-operand from Bs (linear), B-operand from As (padded)
#pragma unroll
      for (int ms = 0; ms < 4; ++ms)
        af[ms] = *(const bf16x8*)&Bs[((w >> 1) * 64 + ms * 16 + l16) * 32 + q4 * 8];
#pragma unroll
      for (int js = 0; js < 4; ++js)
        bfr[js] = *(const bf16x8*)&As[(w & 1) * 64 + js * 16 + l16][q4 * 8];
    } else {
#pragma unroll
      for (int ms = 0; ms < 4; ++ms)
        af[ms] = *(const bf16x8*)&As[(w >> 1) * 64 + ms * 16 + l16][q4 * 8];
#pragma unroll
      for (int js = 0; js < 4; ++js)
        bfr[js] = *(const bf16x8*)&Bs[((w & 1) * 64 + js * 16 + l16) * 32 + q4 * 8];
    }
    __builtin_amdgcn_s_setprio(1);
#pragma unroll
    for (int ms = 0; ms < 4; ++ms)
#pragma unroll
      for (int js = 0; js < 4; ++js)
        acc[ms][js] = MFMA16(af[ms], bfr[js], acc[ms][js]);
    __builtin_amdgcn_s_setprio(0);
  }

  if (t < 2) {
    unsigned short* outp = (t == 0) ? QG : KG;
    const float osc = (t == 0) ? (0.125f * LOG2E) : 1.0f;  // fold softmax scale into Q
    const int h = (n0 >> 6) + (w & 1);
    const size_t hb = (size_t)(b * 16 + h) * 2048;
#pragma unroll
    for (int ms = 0; ms < 4; ++ms)
#pragma unroll
      for (int js = 0; js < 4; ++js) {
        const int c = js * 16 + l16;
#pragma unroll
        for (int r = 0; r < 4; ++r) {
          const int s = sloc + (w >> 1) * 64 + ms * 16 + q4 * 4 + r;
          outp[(hb + s) * 64 + c] = f2bf(acc[ms][js][r] * osc);
        }
      }
  } else {
    const int h = (n0 >> 6) + (w >> 1);
    const size_t hb = (size_t)(b * 16 + h) * 64;
#pragma unroll
    for (int ms = 0; ms < 4; ++ms)
#pragma unroll
      for (int js = 0; js < 4; ++js) {
        const int s = sloc + (w & 1) * 64 + js * 16 + l16;
#pragma unroll
        for (int r = 0; r < 4; ++r) {
          const int c = ms * 16 + q4 * 4 + r;
          VtG[(hb + c) * 2048 + s] = f2bf(acc[ms][js][r]);
        }
      }
  }
}

// ---------------------------------------------------------------------------
// Flash attention, causal. Grid (16*nb bh, 16 pairs), 256 thr (4 waves).
// Block p processes 64-row q-tiles xA=31-p then xB=p SEQUENTIALLY:
// (xA+1)+(xB+1) = 33 iterations for EVERY block -> zero tail idle.
// 1024 blocks = exactly 4/CU. All 4 waves active at every j-tile (no skip).
// Swapped-operand S^T = mfma(K,Q): softmax row is lane-local (q=l16).
// ---------------------------------------------------------------------------
__global__ __launch_bounds__(256, 4)
void flash_kernel(const unsigned short* __restrict__ QG,
                  const unsigned short* __restrict__ KG,
                  const unsigned short* __restrict__ VtG,
                  unsigned short* __restrict__ ObG) {
  const int bh = blockIdx.x;
  const int p = blockIdx.y;                 // 0..15
  const int tid = threadIdx.x;
  const int lane = tid & 63, w = tid >> 6;  // w in 0..3
  const int q4 = lane >> 4, l16 = lane & 15;

  const unsigned short* Kp = KG + (size_t)bh * 2048 * 64;
  const unsigned short* Vp = VtG + (size_t)bh * 64 * 2048;

  __shared__ __align__(16) unsigned short Ks[64][72];       // [s][d]
  __shared__ __align__(16) unsigned short Vs[64][72];       // [dv][s]
  __shared__ __align__(16) unsigned short Plds[4][16][72];  // per-wave P[q][k]

  // staging: 256 threads, each covers 16 shorts of K and of V per tile
  const int sr = tid >> 2, sc = (tid & 3) * 16;
  u32x4 kr0, kr1, vr0, vr1;
  {  // prologue prefetch: tile A, j0 = 0
    kr0 = *(const u32x4*)&Kp[(size_t)sr * 64 + sc];
    kr1 = *(const u32x4*)&Kp[(size_t)sr * 64 + sc + 8];
    vr0 = *(const u32x4*)&Vp[(size_t)sr * 2048 + sc];
    vr1 = *(const u32x4*)&Vp[(size_t)sr * 2048 + sc + 8];
  }

  const int xs0 = 31 - p, xs1 = p;
#pragma unroll 1
  for (int ph = 0; ph < 2; ++ph) {
    const int q0 = (ph == 0 ? xs0 : xs1) * 64;
    const int qw = q0 + w * 16;             // wave's first q-row
    const unsigned short* Qp = QG + ((size_t)bh * 2048 + qw) * 64;
    const bf16x8 qf0 = *(const bf16x8*)&Qp[(size_t)l16 * 64 + q4 * 8];
    const bf16x8 qf1 = *(const bf16x8*)&Qp[(size_t)l16 * 64 + 32 + q4 * 8];

    f32x4 oacc[4] = {};  // O^T: oacc[js][r] = O[q=l16][dv=js*16+q4*4+r]
    float m_i = BIG_NEG, l_part = 0.f;

#pragma unroll 1
    for (int j0 = 0; j0 <= q0; j0 += 64) {
      *(u32x4*)&Ks[sr][sc]     = kr0;
      *(u32x4*)&Ks[sr][sc + 8] = kr1;
      *(u32x4*)&Vs[sr][sc]     = vr0;
      *(u32x4*)&Vs[sr][sc + 8] = vr1;
      __syncthreads();

      // prefetch next tile (T14): next j within phase, or phase B's j0=0
      if (j0 < q0) {
        const int jn = j0 + 64;
        kr0 = *(const u32x4*)&Kp[(size_t)(jn + sr) * 64 + sc];
        kr1 = *(const u32x4*)&Kp[(size_t)(jn + sr) * 64 + sc + 8];
        vr0 = *(const u32x4*)&Vp[(size_t)sr * 2048 + jn + sc];
        vr1 = *(const u32x4*)&Vp[(size_t)sr * 2048 + jn + sc + 8];
      } else if (ph == 0) {
        kr0 = *(const u32x4*)&Kp[(size_t)sr * 64 + sc];
        kr1 = *(const u32x4*)&Kp[(size_t)sr * 64 + sc + 8];
        vr0 = *(const u32x4*)&Vp[(size_t)sr * 2048 + sc];
        vr1 = *(const u32x4*)&Vp[(size_t)sr * 2048 + sc + 8];
      }

      // S^T tile: sacc[js][r] = S[q=l16][k = js*16 + q4*4 + r] (log2 domain)
      f32x4 sacc[4] = {};
      __builtin_amdgcn_s_setprio(1);
#pragma unroll
      for (int js = 0; js < 4; ++js) {
        const bf16x8 kf0 = *(const bf16x8*)&Ks[js * 16 + l16][q4 * 8];
        const bf16x8 kf1 = *(const bf16x8*)&Ks[js * 16 + l16][32 + q4 * 8];
        sacc[js] = MFMA16(kf0, qf0, sacc[js]);
        sacc[js] = MFMA16(kf1, qf1, sacc[js]);
      }
      __builtin_amdgcn_s_setprio(0);

      // causal mask (diag tile only) + in-lane max
      float mloc = BIG_NEG;
      if (j0 == q0) {
        const int qrel = w * 16 + l16;  // row offset within this j-tile
#pragma unroll
        for (int js = 0; js < 4; ++js)
#pragma unroll
          for (int r = 0; r < 4; ++r) {
            const int krel = js * 16 + q4 * 4 + r;
            float v = sacc[js][r];
            if (krel > qrel) v = BIG_NEG;
            sacc[js][r] = v;
            mloc = fmaxf(mloc, v);
          }
      } else {
#pragma unroll
        for (int js = 0; js < 4; ++js)
#pragma unroll
          for (int r = 0; r < 4; ++r) mloc = fmaxf(mloc, sacc[js][r]);
      }
      // row max across the 4 q4-groups sharing q=l16
      mloc = fmaxf(mloc, __shfl_xor(mloc, 16, 64));
      mloc = fmaxf(mloc, __shfl_xor(mloc, 32, 64));

      // defer-max (T13): only rescale when the running max grew past THR
      if (__any(mloc > m_i + DEFER_THR)) {
        const float mnew = fmaxf(m_i, mloc);
        const float alpha = __builtin_amdgcn_exp2f(m_i - mnew);
        m_i = mnew;
        l_part *= alpha;
#pragma unroll
        for (int js = 0; js < 4; ++js)
#pragma unroll
          for (int r = 0; r < 4; ++r) oacc[js][r] *= alpha;
      }

#pragma unroll
      for (int js = 0; js < 4; ++js)
#pragma unroll
        for (int r = 0; r < 4; ++r) {
          const float pv = __builtin_amdgcn_exp2f(sacc[js][r] - m_i);
          sacc[js][r] = pv;
          l_part += pv;  // sum reduce deferred to epilogue
        }

      // P store: row q=l16, 4 consecutive k per js -> one 8B write each
#pragma unroll
      for (int js = 0; js < 4; ++js) {
        u32x2 pk;
        pk[0] = cvtpk(sacc[js][0], sacc[js][1]);
        pk[1] = cvtpk(sacc[js][2], sacc[js][3]);
        *(u32x2*)&Plds[w][l16][js * 16 + q4 * 4] = pk;
      }

      asm volatile("" ::: "memory");

      // B-fragment of P^T: lane needs P[q=l16][k=q4*8..+8]
      const bf16x8 pf0 = *(const bf16x8*)&Plds[w][l16][q4 * 8];
      const bf16x8 pf1 = *(const bf16x8*)&Plds[w][l16][32 + q4 * 8];

      __builtin_amdgcn_s_setprio(1);
#pragma unroll
      for (int js = 0; js < 4; ++js) {
        const bf16x8 vf0 = *(const bf16x8*)&Vs[js * 16 + l16][q4 * 8];
        const bf16x8 vf1 = *(const bf16x8*)&Vs[js * 16 + l16][32 + q4 * 8];
        oacc[js] = MFMA16(vf0, pf0, oacc[js]);
        oacc[js] = MFMA16(vf1, pf1, oacc[js]);
      }
      __builtin_amdgcn_s_setprio(0);
      __syncthreads();  // all LDS reads done before next staging writes
    }

    // phase epilogue: reduce deferred l, write O rows [qw, qw+16)
    float l_i = l_part;
    l_i += __shfl_xor(l_i, 16, 64);
    l_i += __shfl_xor(l_i, 32, 64);

    const int b = bh >> 4, h = bh & 15;
    const int q = qw + l16;
    const float rl = 1.0f / l_i;
    unsigned short* orow = ObG + ((size_t)b * 2048 + q) * 1024 + h * 64;
#pragma unroll
    for (int js = 0; js < 4; ++js) {
      u32x2 ok;
      ok[0] = cvtpk(oacc[js][0] * rl, oacc[js][1] * rl);
      ok[1] = cvtpk(oacc[js][2] * rl, oacc[js][3] * rl);
      *(u32x2*)&orow[js * 16 + q4 * 4] = ok;
    }
  }
}

// ---------------------------------------------------------------------------
// Output projection, GROUP: ObG bf16 [nb*2048][1024] x WoT bf16 [n][d]
// + bo(f32) -> outG f32 [nb*2048][1024].
// 1D grid nwg = 8*MB_CNT, XCD-chunked swizzle, m-major. gl16 staging.
// ---------------------------------------------------------------------------
__global__ __launch_bounds__(256)
void oproj_kernel(const unsigned short* __restrict__ ObG,
                  const unsigned short* __restrict__ WoT,
                  const float* __restrict__ bo,
                  float* __restrict__ outG) {
  const int nwg = gridDim.x;                       // 8 * MB_CNT, %8 == 0
  const int wg = blockIdx.x;
  const int swz = (wg & 7) * (nwg >> 3) + (wg >> 3);
  const int m0 = (swz >> 3) * 128;
  const int n0 = (swz & 7) * 128;

  __shared__ __align__(16) unsigned short As[128 * 32];
  __shared__ __align__(16) unsigned short Bs[128 * 32];

  const int tid = threadIdx.x;
  const int lane = tid & 63, w = tid >> 6;
  const int q4 = lane >> 4, l16 = lane & 15;
  const int lr = lane >> 2, lc = (lane & 3) * 8;

  f32x4 acc[4][4] = {};

  const unsigned short* ga0 = &ObG[(size_t)(m0 + w * 32 + lr) * 1024 + lc];
  const unsigned short* ga1 = ga0 + 16 * 1024;
  const unsigned short* gb0 = &WoT[(size_t)(n0 + w * 32 + lr) * 1024 + lc];
  const unsigned short* gb1 = gb0 + 16 * 1024;
  char* la0 = (char*)As + w * 2048;
  char* lb0 = (char*)Bs + w * 2048;

  for (int k0 = 0; k0 < 1024; k0 += 32) {
    __syncthreads();
    gl16(ga0 + k0, la0);
    gl16(ga1 + k0, la0 + 1024);
    gl16(gb0 + k0, lb0);
    gl16(gb1 + k0, lb0 + 1024);
    __syncthreads();

    bf16x8 af[4], bfr[4];
#pragma unroll
    for (int ms = 0; ms < 4; ++ms)
      af[ms] = *(const bf16x8*)&As[((w >> 1) * 64 + ms * 16 + l16) * 32 + q4 * 8];
#pragma unroll
    for (int js = 0; js < 4; ++js)
      bfr[js] = *(const bf16x8*)&Bs[((w & 1) * 64 + js * 16 + l16) * 32 + q4 * 8];
    __builtin_amdgcn_s_setprio(1);
#pragma unroll
    for (int ms = 0; ms < 4; ++ms)
#pragma unroll
      for (int js = 0; js < 4; ++js)
        acc[ms][js] = MFMA16(af[ms], bfr[js], acc[ms][js]);
    __builtin_amdgcn_s_setprio(0);
  }

#pragma unroll
  for (int js = 0; js < 4; ++js) {
    const int col = n0 + (w & 1) * 64 + js * 16 + l16;
    const float bias = bo[col];
#pragma unroll
    for (int ms = 0; ms < 4; ++ms)
#pragma unroll
      for (int r = 0; r < 4; ++r) {
        const int row = m0 + (w >> 1) * 64 + ms * 16 + q4 * 4 + r;
        outG[(size_t)row * 1024 + col] = acc[ms][js][r] + bias;  // f32 store
      }
  }
}

// ---------------------------------------------------------------------------
extern "C" void kernel_launch(void* const* d_in, const int* in_sizes, int n_in,
                              void* d_out, int out_size, void* d_ws, size_t ws_size,
                              hipStream_t stream) {
  const float* emb = (const float*)d_in[0];   // [4][2048][1024] f32
  const float* Wq  = (const float*)d_in[1];   // [16][1024][64]  f32
  const float* Wk  = (const float*)d_in[2];
  const float* Wv  = (const float*)d_in[3];
  const float* Wo  = (const float*)d_in[4];   // [1024][1024]    f32
  const float* bo  = (const float*)d_in[5];   // [1024]          f32
  float* out = (float*)d_out;                 // [4][2048][1024] f32

  char* ws = (char*)d_ws;
  const size_t MB = 1024 * 1024;

  // group size: nb batches per pipeline pass. ws need = 8 + 16*nb MB.
  const int nb = (ws_size >= 72 * MB) ? 4 : (ws_size >= 40 * MB) ? 2 : 1;

  unsigned short* WqT = (unsigned short*)(ws + 0 * MB);              // 2 MB [h][c][d]
  unsigned short* WkT = (unsigned short*)(ws + 2 * MB);              // 2 MB
  unsigned short* WvT = (unsigned short*)(ws + 4 * MB);              // 2 MB
  unsigned short* WoT = (unsigned short*)(ws + 6 * MB);              // 2 MB [n][d]
  unsigned short* QG  = (unsigned short*)(ws + 8 * MB);              // 4*nb MB
  unsigned short* KG  = (unsigned short*)(ws + (8 + 4 * nb) * MB);   // 4*nb MB
  unsigned short* VtG = (unsigned short*)(ws + (8 + 8 * nb) * MB);   // 4*nb MB
  unsigned short* ObG = (unsigned short*)(ws + (8 + 12 * nb) * MB);  // 4*nb MB

  const dim3 tb(32, 8, 1);
  wtrans_kernel<<<dim3(2, 32, 16), tb, 0, stream>>>(Wq, WqT, 1024, 64);
  wtrans_kernel<<<dim3(2, 32, 16), tb, 0, stream>>>(Wk, WkT, 1024, 64);
  wtrans_kernel<<<dim3(2, 32, 16), tb, 0, stream>>>(Wv, WvT, 1024, 64);
  wtrans_kernel<<<dim3(32, 32, 1), tb, 0, stream>>>(Wo, WoT, 1024, 1024);

  for (int g = 0; g < 4; g += nb) {
    const float* embG = emb + (size_t)g * 2048 * 1024;
    float* outG = out + (size_t)g * 2048 * 1024;
    qkv_kernel<<<dim3(24 * 16 * nb), 256, 0, stream>>>(embG, WqT, WkT, WvT, QG, KG, VtG);
    flash_kernel<<<dim3(16 * nb, 16), 256, 0, stream>>>(QG, KG, VtG, ObG);
    oproj_kernel<<<dim3(8 * 16 * nb), 256, 0, stream>>>(ObG, WoT, bo, outG);
  }
}